// Round 11
// baseline (568.834 us; speedup 1.0000x reference)
//
#include <hip/hip_runtime.h>

// Problem constants (setup_inputs fixed: 48x48 input, 192x192 output, factor=4)
#define NXY   48
#define NG    2304      // 48*48 gaussians
#define KDIM  288       // 32*9 unfolded feature dim
#define HID   256
#define NHID  1024      // 4 heads * 256
#define HW    192
#define NPIX  (HW*HW)   // 36864
#define NCHUNK (NG/64)  // 36 gaussian chunks of 64
#define NB    576       // grid size; co-resident (>=4 blocks/CU via launch_bounds)
#define BAR_STRIDE 1024

typedef __bf16 bf16x8 __attribute__((ext_vector_type(8)));
typedef float  f32x4  __attribute__((ext_vector_type(4)));
typedef unsigned short ushort_t;
typedef unsigned int   uint_t;

__device__ __forceinline__ ushort_t f2bf(float x) {          // RNE float->bf16 bits
    uint_t u = __float_as_uint(x);
    uint_t r = u + 0x7FFFu + ((u >> 16) & 1u);
    return (ushort_t)(r >> 16);
}
__device__ __forceinline__ float bf2f(ushort_t h) {
    return __uint_as_float(((uint_t)h) << 16);
}

// Contention-free grid barrier (R10 A/B: only the barrier internals changed).
// Arrive: per-block flag store (distinct words, no RMW contention).
// Gather: block 0 sweeps flags. Release: single word, read-only spin.
__device__ __forceinline__ void gbar(uint_t* arr, uint_t* rel, int phase) {
    const int bx = blockIdx.x, tid = threadIdx.x;
    __syncthreads();
    if (tid == 0) {
        __threadfence();                        // release this block's stores
        __hip_atomic_store(arr + phase * BAR_STRIDE + bx, 1u,
                           __ATOMIC_RELEASE, __HIP_MEMORY_SCOPE_AGENT);
    }
    if (bx == 0) {
        for (;;) {
            uint_t ok = 1u;
            for (int i = tid; i < NB; i += 256)
                ok &= __hip_atomic_load(arr + phase * BAR_STRIDE + i,
                                        __ATOMIC_ACQUIRE, __HIP_MEMORY_SCOPE_AGENT);
            if (__syncthreads_and((int)ok)) break;
            __builtin_amdgcn_s_sleep(8);
        }
        if (tid == 0)
            __hip_atomic_store(rel + phase, 1u,
                               __ATOMIC_RELEASE, __HIP_MEMORY_SCOPE_AGENT);
        __syncthreads();
    } else {
        if (tid == 0) {
            while (!__hip_atomic_load(rel + phase, __ATOMIC_ACQUIRE,
                                      __HIP_MEMORY_SCOPE_AGENT))
                __builtin_amdgcn_s_sleep(32);
        }
        __syncthreads();
    }
    __threadfence();                            // acquire remote stores
}

struct Params {
    const float *inp, *cw, *cb;
    const float *w1o, *w1s, *w1r, *w1c;
    const float *b1o, *b1s, *b1r, *b1c;
    const float *ow2, *ob2, *sw2, *sb2, *rw2, *rb2, *cw2, *cb2;
    ushort_t *Ahi, *Alo, *Bph, *Bpl;
    float* hid;
    float4 *gbox, *gdat;
    uint_t *barA, *barR;
    float* out;
};

// Single persistent kernel: 576 blocks x 256 threads, 4 phases / 3 barriers.
// 576 = 2304/4 gaussian groups = 36x16 gemm tiles = 24x24 render tiles.
__global__ __launch_bounds__(256, 4) void fused2_k(Params p) {
    __shared__ float  convT[3][6][32];  // P1: conv halo tile (xs, ys, c)
    __shared__ float4 ldsE[4][64][2];   // P4: per-wave survivor list
    __shared__ float  red[4][64][3];    // P4: cross-wave reduction
    const int bx   = blockIdx.x;
    const int tid  = threadIdx.x;
    const int lane = tid & 63;
    const int wv   = tid >> 6;

    // ===== P1: fused conv3x3+unfold+LN (tiles 0..575) | W1 pack (576..719) =====
    for (int t = bx; t < 720; t += NB) {
        if (t < 576) {
            int n0 = t * 4;
            int x  = n0 / NXY;          // 4 gaussians share x (48%4==0)
            int y0 = n0 % NXY;
            // conv halo: c in [0,32), h = y0-1+ys (ys<6), w = x-1+xs (xs<3)
            for (int i = tid; i < 576; i += 256) {
                int c  = i & 31;
                int ys = (i >> 5) % 6;
                int xs = i / 192;
                int w_ = x - 1 + xs, h_ = y0 - 1 + ys;
                float acc = 0.f;
                if (w_ >= 0 && w_ < NXY && h_ >= 0 && h_ < NXY) {
                    acc = p.cb[c];
                    #pragma unroll
                    for (int i3 = 0; i3 < 3; ++i3)
                        #pragma unroll
                        for (int kh = 0; kh < 3; ++kh) {
                            int hh = h_ + kh - 1;
                            if (hh < 0 || hh >= NXY) continue;
                            #pragma unroll
                            for (int kw = 0; kw < 3; ++kw) {
                                int ww = w_ + kw - 1;
                                if (ww < 0 || ww >= NXY) continue;
                                acc = fmaf(p.inp[(i3 * NXY + hh) * NXY + ww],
                                           p.cw[((c * 3 + i3) * 3 + kh) * 3 + kw], acc);
                            }
                        }
                }
                convT[xs][ys][c] = acc;
            }
            __syncthreads();
            // LN: wave wv -> gaussian n0+wv; tile read [ki][wv+kj][c]
            {
                int n = n0 + wv;
                float v[5];
                float sum = 0.f, sq = 0.f;
                #pragma unroll
                for (int i5 = 0; i5 < 5; ++i5) {
                    int k = lane + 64 * i5;
                    float val = 0.f;
                    if (k < KDIM) {
                        int c = k / 9, r = k % 9, ki = r / 3, kj = r % 3;
                        val = convT[ki][wv + kj][c];
                    }
                    v[i5] = val; sum += val; sq = fmaf(val, val, sq);
                }
                #pragma unroll
                for (int off = 32; off; off >>= 1) {
                    sum += __shfl_xor(sum, off);
                    sq  += __shfl_xor(sq,  off);
                }
                float mean = sum * (1.0f / KDIM);
                float var  = sq * (1.0f / KDIM) - mean * mean;
                float rstd = rsqrtf(var + 1e-5f);
                #pragma unroll
                for (int i5 = 0; i5 < 5; ++i5) {
                    int k = lane + 64 * i5;
                    if (k < KDIM) {
                        float w = (v[i5] - mean) * rstd;
                        ushort_t hb = f2bf(w);
                        p.Ahi[n * KDIM + k] = hb;
                        p.Alo[n * KDIM + k] = f2bf(w - bf2f(hb));
                    }
                }
            }
            __syncthreads();
        } else {
            // Bp[((nf*9+ks)*64+l)*8+i] = W[ks*32+(l>>4)*8+i][nf*16+(l&15)]
            int t2 = (t - 576) * 256 + tid;
            int l = t2 & 63, tt = t2 >> 6;
            int ks = tt % 9, nf = tt / 9;
            int ncol = nf * 16 + (l & 15);
            int head = ncol >> 8, c = ncol & 255;
            const float* w = head == 0 ? p.w1o : head == 1 ? p.w1s
                           : head == 2 ? p.w1r : p.w1c;
            int kbase = ks * 32 + (l >> 4) * 8;
            #pragma unroll
            for (int i = 0; i < 8; ++i) {
                float xv = w[(kbase + i) * HID + c];
                ushort_t hb = f2bf(xv);
                p.Bph[t2 * 8 + i] = hb;
                p.Bpl[t2 * 8 + i] = f2bf(xv - bf2f(hb));
            }
        }
    }
    gbar(p.barA, p.barR, 0);

    // ===== P2: MFMA GEMM (576 64x64 tiles) + bias + ReLU =====
    // Split-bf16 3-product: C = Ahi*Bhi + Ahi*Blo + Alo*Bhi (~fp32 accuracy).
    {
        int t = bx;
        int m0  = (t >> 4) * 64 + (wv >> 1) * 32;
        int nf0 = (t & 15) * 4 + (wv & 1) * 2;
        int r15 = lane & 15, kg = lane >> 4;
        f32x4 acc[2][2] = {};
        const ushort_t* pah = p.Ahi + (m0 + r15) * KDIM + kg * 8;
        const ushort_t* pal = p.Alo + (m0 + r15) * KDIM + kg * 8;
        #pragma unroll 3
        for (int ks = 0; ks < 9; ++ks) {
            bf16x8 ah[2], al[2], bh[2], bl[2];
            #pragma unroll
            for (int m = 0; m < 2; ++m) {
                ah[m] = *(const bf16x8*)(pah + m * 16 * KDIM + ks * 32);
                al[m] = *(const bf16x8*)(pal + m * 16 * KDIM + ks * 32);
            }
            #pragma unroll
            for (int n = 0; n < 2; ++n) {
                size_t off = ((size_t)((nf0 + n) * 9 + ks) * 64 + lane) * 8;
                bh[n] = *(const bf16x8*)(p.Bph + off);
                bl[n] = *(const bf16x8*)(p.Bpl + off);
            }
            #pragma unroll
            for (int m = 0; m < 2; ++m)
                #pragma unroll
                for (int n = 0; n < 2; ++n) {
                    acc[m][n] = __builtin_amdgcn_mfma_f32_16x16x32_bf16(ah[m], bh[n], acc[m][n], 0, 0, 0);
                    acc[m][n] = __builtin_amdgcn_mfma_f32_16x16x32_bf16(ah[m], bl[n], acc[m][n], 0, 0, 0);
                    acc[m][n] = __builtin_amdgcn_mfma_f32_16x16x32_bf16(al[m], bh[n], acc[m][n], 0, 0, 0);
                }
        }
        // C/D layout: col = lane&15, row = (lane>>4)*4 + reg  [m89-verified]
        #pragma unroll
        for (int n = 0; n < 2; ++n) {
            int col = (nf0 + n) * 16 + r15;
            int head = col >> 8;
            const float* bb = head == 0 ? p.b1o : head == 1 ? p.b1s
                            : head == 2 ? p.b1r : p.b1c;
            float bias = bb[col & 255];
            #pragma unroll
            for (int m = 0; m < 2; ++m)
                #pragma unroll
                for (int r = 0; r < 4; ++r) {
                    int grow = m0 + m * 16 + kg * 4 + r;
                    p.hid[(size_t)grow * NHID + col] = fmaxf(acc[m][n][r] + bias, 0.f);
                }
        }
    }
    gbar(p.barA, p.barR, 1);

    // ===== P3: per-gaussian head dots + conic + bbox =====
    {
        int n = bx * 4 + wv;
        const float* h = p.hid + (size_t)n * NHID;
        float s[8] = {};
        #pragma unroll
        for (int i = 0; i < 4; ++i) {
            int j = lane + 64 * i;
            float h0 = h[j], h1 = h[256 + j], h2 = h[512 + j], h3 = h[768 + j];
            s[0] = fmaf(h0, p.ow2[j * 2 + 0], s[0]);
            s[1] = fmaf(h0, p.ow2[j * 2 + 1], s[1]);
            s[2] = fmaf(h1, p.sw2[j * 2 + 0], s[2]);
            s[3] = fmaf(h1, p.sw2[j * 2 + 1], s[3]);
            s[4] = fmaf(h2, p.rw2[j],         s[4]);
            s[5] = fmaf(h3, p.cw2[j * 3 + 0], s[5]);
            s[6] = fmaf(h3, p.cw2[j * 3 + 1], s[6]);
            s[7] = fmaf(h3, p.cw2[j * 3 + 2], s[7]);
        }
        #pragma unroll
        for (int off = 32; off; off >>= 1)
            #pragma unroll
            for (int k = 0; k < 8; ++k) s[k] += __shfl_xor(s[k], off);
        if (lane == 0) {
            float o0 = s[0] + p.ob2[0], o1 = s[1] + p.ob2[1];
            float z0 = s[2] + p.sb2[0], z1 = s[3] + p.sb2[1];
            float zr = s[4] + p.rb2[0];
            float c0 = s[5] + p.cb2[0], c1 = s[6] + p.cb2[1], c2 = s[7] + p.cb2[2];
            int x = n / NXY, y = n % NXY;
            // off_factor = 2*4/192 -> offset = tanh*3*off_factor = tanh*0.125
            float ndcx = ((x + 0.5f) * (2.0f / NXY) - 1.0f) + tanhf(o0) * 0.125f;
            float ndcy = ((y + 0.5f) * (2.0f / NXY) - 1.0f) + tanhf(o1) * 0.125f;
            float cxp = 0.5f * ((ndcx + 1.0f) * HW - 1.0f);
            float cyp = 0.5f * ((ndcy + 1.0f) * HW - 1.0f);
            float sx = 8.0f / (1.0f + expf(-z0));   // sigmoid * 2 * factor
            float sy = 8.0f / (1.0f + expf(-z1));
            float rot = 6.283185307179586f / (1.0f + expf(-zr));
            float cc = cosf(rot), ss = sinf(rot);
            float sx2 = sx * sx, sy2 = sy * sy;
            float cov00 = cc * cc * sx2 + ss * ss * sy2;
            float cov01 = cc * ss * (sx2 - sy2);
            float cov11 = ss * ss * sx2 + cc * cc * sy2;
            float det = cov00 * cov11 - cov01 * cov01;
            float inv = 1.0f / det;
            float A = cov11 * inv, Bc = -cov01 * inv, Cc = cov00 * inv;
            // bbox of {alpha >= 1/255}: |dx| <= sqrt(2*tau*cov00), tau=ln255
            float rx = sqrtf(11.2f * cov00) + 1e-2f;
            float ry = sqrtf(11.2f * cov11) + 1e-2f;
            p.gbox[n]         = make_float4(cxp, cyp, rx, ry);
            p.gdat[2 * n]     = make_float4(0.5f * A, Bc, 0.5f * Cc, tanhf(c0));
            p.gdat[2 * n + 1] = make_float4(tanhf(c1), tanhf(c2), 0.f, 0.f);
        }
    }
    gbar(p.barA, p.barR, 2);

    // ===== P4: render (576 8x8 tiles), 4 waves split gaussians, culled =====
    {
        int t = bx;
        int tx0 = (t % 24) * 8, ty0 = (t / 24) * 8;
        float px = (float)(tx0 + (lane & 7));
        float py = (float)(ty0 + (lane >> 3));
        float xlo = (float)tx0, xhi = (float)(tx0 + 7);
        float ylo = (float)ty0, yhi = (float)(ty0 + 7);
        float ar = 0.f, ag = 0.f, ab = 0.f;
        for (int c = wv; c < NCHUNK; c += 4) {
            int g = c * 64 + lane;
            float4 bb = p.gbox[g];
            bool pred = (bb.x - bb.z <= xhi) && (bb.x + bb.z >= xlo) &&
                        (bb.y - bb.w <= yhi) && (bb.y + bb.w >= ylo);
            unsigned long long m = __ballot(pred);
            int cnt = __popcll(m);
            int pos = __popcll(m & ((1ull << lane) - 1ull));
            if (pred) {
                float4 d0 = p.gdat[2 * g];
                float4 d1 = p.gdat[2 * g + 1];
                ldsE[wv][pos][0] = make_float4(bb.x, bb.y, d0.x, d0.y);  // cx cy .5A B
                ldsE[wv][pos][1] = make_float4(d0.z, d0.w, d1.x, d1.y);  // .5C r g b
            }
            asm volatile("s_waitcnt lgkmcnt(0)" ::: "memory");
            for (int i = 0; i < cnt; ++i) {
                float4 e0 = ldsE[wv][i][0];
                float4 e1 = ldsE[wv][i][1];
                float dx = px - e0.x;
                float dy = py - e0.y;
                float sigma = fmaf(dx, fmaf(e0.z, dx, e0.w * dy), e1.x * dy * dy);
                float a = __expf(-sigma);
                a = (a >= (1.0f / 255.0f)) ? a : 0.f;
                ar = fmaf(a, e1.y, ar);
                ag = fmaf(a, e1.z, ag);
                ab = fmaf(a, e1.w, ab);
            }
        }
        red[wv][lane][0] = ar; red[wv][lane][1] = ag; red[wv][lane][2] = ab;
        __syncthreads();
        if (wv == 0) {
            float r_ = red[0][lane][0] + red[1][lane][0] + red[2][lane][0] + red[3][lane][0];
            float g_ = red[0][lane][1] + red[1][lane][1] + red[2][lane][1] + red[3][lane][1];
            float b_ = red[0][lane][2] + red[1][lane][2] + red[2][lane][2] + red[3][lane][2];
            int pix = (ty0 + (lane >> 3)) * HW + tx0 + (lane & 7);
            p.out[pix]            = fminf(fmaxf(r_, 0.f), 1.f);
            p.out[NPIX + pix]     = fminf(fmaxf(g_, 0.f), 1.f);
            p.out[2 * NPIX + pix] = fminf(fmaxf(b_, 0.f), 1.f);
        }
    }
}

extern "C" void kernel_launch(void* const* d_in, const int* in_sizes, int n_in,
                              void* d_out, int out_size, void* d_ws, size_t ws_size,
                              hipStream_t stream) {
    float* ws = (float*)d_ws;
    Params p;
    p.inp = (const float*)d_in[0];
    p.cw  = (const float*)d_in[1];
    p.cb  = (const float*)d_in[2];
    p.w1o = (const float*)d_in[3];
    p.b1o = (const float*)d_in[4];
    p.ow2 = (const float*)d_in[5];
    p.ob2 = (const float*)d_in[6];
    p.w1s = (const float*)d_in[7];
    p.b1s = (const float*)d_in[8];
    p.sw2 = (const float*)d_in[9];
    p.sb2 = (const float*)d_in[10];
    p.w1r = (const float*)d_in[11];
    p.b1r = (const float*)d_in[12];
    p.rw2 = (const float*)d_in[13];
    p.rb2 = (const float*)d_in[14];
    p.w1c = (const float*)d_in[15];
    p.b1c = (const float*)d_in[16];
    p.cw2 = (const float*)d_in[17];
    p.cb2 = (const float*)d_in[18];

    p.hid  = ws;                               // 2359296 f
    p.gbox = (float4*)(ws + 2359296);          // 2304 float4
    p.gdat = (float4*)(ws + 2368512);          // 4608 float4
    p.Ahi  = (ushort_t*)(ws + 2386944);        // 663552 us
    p.Alo  = (ushort_t*)(ws + 2718720);        // 663552 us
    p.Bph  = (ushort_t*)(ws + 3050496);        // 294912 us
    p.Bpl  = (ushort_t*)(ws + 3197952);        // 294912 us
    p.barA = (uint_t*)(ws + 3345408);          // 3*1024 arrive flags
    p.barR = p.barA + 3 * BAR_STRIDE;          // 3 release words
    p.out  = (float*)d_out;

    hipMemsetAsync(p.barA, 0, 16384, stream);  // zero flags+release (capture-safe)
    hipLaunchKernelGGL(fused2_k, dim3(NB), dim3(256), 0, stream, p);
}

// Round 12
// 50.889 us; speedup vs baseline: 11.1779x; 11.1779x over previous
//
#include <hip/hip_runtime.h>

// Problem constants (setup_inputs fixed: 48x48 input, 192x192 output, factor=4)
#define NXY   48
#define NG    2304      // 48*48 gaussians
#define KDIM  288       // 32*9 unfolded feature dim
#define HID   256
#define NHID  1024      // 4 heads * 256
#define HW    192
#define NPIX  (HW*HW)   // 36864
#define NCHUNK (NG/64)  // 36 gaussian chunks of 64

typedef __bf16 bf16x8 __attribute__((ext_vector_type(8)));
typedef float  f32x4  __attribute__((ext_vector_type(4)));
typedef unsigned short ushort_t;
typedef unsigned int   uint_t;

__device__ __forceinline__ ushort_t f2bf(float x) {          // RNE float->bf16 bits
    uint_t u = __float_as_uint(x);
    uint_t r = u + 0x7FFFu + ((u >> 16) & 1u);
    return (ushort_t)(r >> 16);
}
__device__ __forceinline__ float bf2f(ushort_t h) {
    return __uint_as_float(((uint_t)h) << 16);
}

// ===== prep: fused conv3x3+unfold+LN (blocks 0..575) | W1 pack (576..719) ===
// R10-P1 verified body. No global feat buffer: conv tile lives in LDS.
__global__ __launch_bounds__(256) void prep_k(const float* __restrict__ inp,
        const float* __restrict__ cw, const float* __restrict__ cb,
        const float* __restrict__ w1o, const float* __restrict__ w1s,
        const float* __restrict__ w1r, const float* __restrict__ w1c,
        ushort_t* __restrict__ Ahi, ushort_t* __restrict__ Alo,
        ushort_t* __restrict__ Bph, ushort_t* __restrict__ Bpl) {
    __shared__ float convT[3][6][32];   // (xs, ys, c) halo tile
    const int t    = blockIdx.x;
    const int tid  = threadIdx.x;
    const int lane = tid & 63;
    const int wv   = tid >> 6;
    if (t < 576) {
        int n0 = t * 4;
        int x  = n0 / NXY;              // 4 gaussians share x (48%4==0)
        int y0 = n0 % NXY;
        // conv halo: c in [0,32), h = y0-1+ys (ys<6), w = x-1+xs (xs<3)
        for (int i = tid; i < 576; i += 256) {
            int c  = i & 31;
            int ys = (i >> 5) % 6;
            int xs = i / 192;
            int w_ = x - 1 + xs, h_ = y0 - 1 + ys;
            float acc = 0.f;
            if (w_ >= 0 && w_ < NXY && h_ >= 0 && h_ < NXY) {
                acc = cb[c];
                #pragma unroll
                for (int i3 = 0; i3 < 3; ++i3)
                    #pragma unroll
                    for (int kh = 0; kh < 3; ++kh) {
                        int hh = h_ + kh - 1;
                        if (hh < 0 || hh >= NXY) continue;
                        #pragma unroll
                        for (int kw = 0; kw < 3; ++kw) {
                            int ww = w_ + kw - 1;
                            if (ww < 0 || ww >= NXY) continue;
                            acc = fmaf(inp[(i3 * NXY + hh) * NXY + ww],
                                       cw[((c * 3 + i3) * 3 + kh) * 3 + kw], acc);
                        }
                    }
            }
            convT[xs][ys][c] = acc;
        }
        __syncthreads();
        // LN: wave wv -> gaussian n0+wv; tile read [ki][wv+kj][c]
        int n = n0 + wv;
        float v[5];
        float sum = 0.f, sq = 0.f;
        #pragma unroll
        for (int i5 = 0; i5 < 5; ++i5) {
            int k = lane + 64 * i5;
            float val = 0.f;
            if (k < KDIM) {
                int c = k / 9, r = k % 9, ki = r / 3, kj = r % 3;
                val = convT[ki][wv + kj][c];
            }
            v[i5] = val; sum += val; sq = fmaf(val, val, sq);
        }
        #pragma unroll
        for (int off = 32; off; off >>= 1) {
            sum += __shfl_xor(sum, off);
            sq  += __shfl_xor(sq,  off);
        }
        float mean = sum * (1.0f / KDIM);
        float var  = sq * (1.0f / KDIM) - mean * mean;
        float rstd = rsqrtf(var + 1e-5f);
        #pragma unroll
        for (int i5 = 0; i5 < 5; ++i5) {
            int k = lane + 64 * i5;
            if (k < KDIM) {
                float w = (v[i5] - mean) * rstd;
                ushort_t hb = f2bf(w);
                Ahi[n * KDIM + k] = hb;
                Alo[n * KDIM + k] = f2bf(w - bf2f(hb));
            }
        }
    } else {
        // Bp[((nf*9+ks)*64+l)*8+i] = W[ks*32+(l>>4)*8+i][nf*16+(l&15)]
        int t2 = (t - 576) * 256 + tid;
        int l = t2 & 63, tt = t2 >> 6;
        int ks = tt % 9, nf = tt / 9;
        int ncol = nf * 16 + (l & 15);
        int head = ncol >> 8, c = ncol & 255;
        const float* w = head == 0 ? w1o : head == 1 ? w1s
                       : head == 2 ? w1r : w1c;
        int kbase = ks * 32 + (l >> 4) * 8;
        #pragma unroll
        for (int i = 0; i < 8; ++i) {
            float xv = w[(kbase + i) * HID + c];
            ushort_t hb = f2bf(xv);
            Bph[t2 * 8 + i] = hb;
            Bpl[t2 * 8 + i] = f2bf(xv - bf2f(hb));
        }
    }
}

// ===== gemm: MFMA [2304x288]@[288x1024] + bias + ReLU (R10-P2 body) ========
// Split-bf16 3-product: C = Ahi*Bhi + Ahi*Blo + Alo*Bhi (~fp32 accuracy).
__global__ __launch_bounds__(256) void gemm_k(const ushort_t* __restrict__ Ahi,
        const ushort_t* __restrict__ Alo,
        const ushort_t* __restrict__ Bph, const ushort_t* __restrict__ Bpl,
        const float* __restrict__ b1o, const float* __restrict__ b1s,
        const float* __restrict__ b1r, const float* __restrict__ b1c,
        float* __restrict__ hid) {
    const int t    = blockIdx.x;
    const int lane = threadIdx.x & 63;
    const int wv   = threadIdx.x >> 6;
    int m0  = (t >> 4) * 64 + (wv >> 1) * 32;
    int nf0 = (t & 15) * 4 + (wv & 1) * 2;
    int r15 = lane & 15, kg = lane >> 4;
    f32x4 acc[2][2] = {};
    const ushort_t* pah = Ahi + (m0 + r15) * KDIM + kg * 8;
    const ushort_t* pal = Alo + (m0 + r15) * KDIM + kg * 8;
    #pragma unroll 3
    for (int ks = 0; ks < 9; ++ks) {
        bf16x8 ah[2], al[2], bh[2], bl[2];
        #pragma unroll
        for (int m = 0; m < 2; ++m) {
            ah[m] = *(const bf16x8*)(pah + m * 16 * KDIM + ks * 32);
            al[m] = *(const bf16x8*)(pal + m * 16 * KDIM + ks * 32);
        }
        #pragma unroll
        for (int n = 0; n < 2; ++n) {
            size_t off = ((size_t)((nf0 + n) * 9 + ks) * 64 + lane) * 8;
            bh[n] = *(const bf16x8*)(Bph + off);
            bl[n] = *(const bf16x8*)(Bpl + off);
        }
        #pragma unroll
        for (int m = 0; m < 2; ++m)
            #pragma unroll
            for (int n = 0; n < 2; ++n) {
                acc[m][n] = __builtin_amdgcn_mfma_f32_16x16x32_bf16(ah[m], bh[n], acc[m][n], 0, 0, 0);
                acc[m][n] = __builtin_amdgcn_mfma_f32_16x16x32_bf16(ah[m], bl[n], acc[m][n], 0, 0, 0);
                acc[m][n] = __builtin_amdgcn_mfma_f32_16x16x32_bf16(al[m], bh[n], acc[m][n], 0, 0, 0);
            }
    }
    // C/D layout: col = lane&15, row = (lane>>4)*4 + reg  [m89-verified]
    #pragma unroll
    for (int n = 0; n < 2; ++n) {
        int col = (nf0 + n) * 16 + r15;
        int head = col >> 8;
        const float* bb = head == 0 ? b1o : head == 1 ? b1s
                        : head == 2 ? b1r : b1c;
        float bias = bb[col & 255];
        #pragma unroll
        for (int m = 0; m < 2; ++m)
            #pragma unroll
            for (int r = 0; r < 4; ++r) {
                int grow = m0 + m * 16 + kg * 4 + r;
                hid[(size_t)grow * NHID + col] = fmaxf(acc[m][n][r] + bias, 0.f);
            }
    }
}

// ===== head: per-gaussian dots + conic + bbox (R10-P3 body) =================
__global__ __launch_bounds__(256) void head_k(const float* __restrict__ hid,
        const float* __restrict__ ow2, const float* __restrict__ ob2,
        const float* __restrict__ sw2, const float* __restrict__ sb2,
        const float* __restrict__ rw2, const float* __restrict__ rb2,
        const float* __restrict__ cw2, const float* __restrict__ cb2,
        float4* __restrict__ gbox, float4* __restrict__ gdat) {
    const int lane = threadIdx.x & 63;
    const int wv   = threadIdx.x >> 6;
    int n = blockIdx.x * 4 + wv;
    const float* h = hid + (size_t)n * NHID;
    float s[8] = {};
    #pragma unroll
    for (int i = 0; i < 4; ++i) {
        int j = lane + 64 * i;
        float h0 = h[j], h1 = h[256 + j], h2 = h[512 + j], h3 = h[768 + j];
        s[0] = fmaf(h0, ow2[j * 2 + 0], s[0]);
        s[1] = fmaf(h0, ow2[j * 2 + 1], s[1]);
        s[2] = fmaf(h1, sw2[j * 2 + 0], s[2]);
        s[3] = fmaf(h1, sw2[j * 2 + 1], s[3]);
        s[4] = fmaf(h2, rw2[j],         s[4]);
        s[5] = fmaf(h3, cw2[j * 3 + 0], s[5]);
        s[6] = fmaf(h3, cw2[j * 3 + 1], s[6]);
        s[7] = fmaf(h3, cw2[j * 3 + 2], s[7]);
    }
    #pragma unroll
    for (int off = 32; off; off >>= 1)
        #pragma unroll
        for (int k = 0; k < 8; ++k) s[k] += __shfl_xor(s[k], off);
    if (lane == 0) {
        float o0 = s[0] + ob2[0], o1 = s[1] + ob2[1];
        float z0 = s[2] + sb2[0], z1 = s[3] + sb2[1];
        float zr = s[4] + rb2[0];
        float c0 = s[5] + cb2[0], c1 = s[6] + cb2[1], c2 = s[7] + cb2[2];
        int x = n / NXY, y = n % NXY;
        // off_factor = 2*4/192 -> offset = tanh*3*off_factor = tanh*0.125
        float ndcx = ((x + 0.5f) * (2.0f / NXY) - 1.0f) + tanhf(o0) * 0.125f;
        float ndcy = ((y + 0.5f) * (2.0f / NXY) - 1.0f) + tanhf(o1) * 0.125f;
        float cxp = 0.5f * ((ndcx + 1.0f) * HW - 1.0f);
        float cyp = 0.5f * ((ndcy + 1.0f) * HW - 1.0f);
        float sx = 8.0f / (1.0f + expf(-z0));   // sigmoid * 2 * factor
        float sy = 8.0f / (1.0f + expf(-z1));
        float rot = 6.283185307179586f / (1.0f + expf(-zr));
        float cc = cosf(rot), ss = sinf(rot);
        float sx2 = sx * sx, sy2 = sy * sy;
        float cov00 = cc * cc * sx2 + ss * ss * sy2;
        float cov01 = cc * ss * (sx2 - sy2);
        float cov11 = ss * ss * sx2 + cc * cc * sy2;
        float det = cov00 * cov11 - cov01 * cov01;
        float inv = 1.0f / det;
        float A = cov11 * inv, Bc = -cov01 * inv, Cc = cov00 * inv;
        // bbox of {alpha >= 1/255}: |dx| <= sqrt(2*tau*cov00), tau=ln255
        float rx = sqrtf(11.2f * cov00) + 1e-2f;
        float ry = sqrtf(11.2f * cov11) + 1e-2f;
        gbox[n]         = make_float4(cxp, cyp, rx, ry);
        gdat[2 * n]     = make_float4(0.5f * A, Bc, 0.5f * Cc, tanhf(c0));
        gdat[2 * n + 1] = make_float4(tanhf(c1), tanhf(c2), 0.f, 0.f);
    }
}

// ===== render: 576 8x8 tiles, 4 waves split gaussians, culled (R10-P4) ======
__global__ __launch_bounds__(256) void render_k(const float4* __restrict__ gbox,
        const float4* __restrict__ gdat, float* __restrict__ out) {
    __shared__ float4 ldsE[4][64][2];
    __shared__ float  red[4][64][3];
    const int t    = blockIdx.x;
    const int lane = threadIdx.x & 63;
    const int wv   = threadIdx.x >> 6;
    int tx0 = (t % 24) * 8, ty0 = (t / 24) * 8;
    float px = (float)(tx0 + (lane & 7));
    float py = (float)(ty0 + (lane >> 3));
    float xlo = (float)tx0, xhi = (float)(tx0 + 7);
    float ylo = (float)ty0, yhi = (float)(ty0 + 7);
    float ar = 0.f, ag = 0.f, ab = 0.f;
    for (int c = wv; c < NCHUNK; c += 4) {
        int g = c * 64 + lane;
        float4 bb = gbox[g];
        bool pred = (bb.x - bb.z <= xhi) && (bb.x + bb.z >= xlo) &&
                    (bb.y - bb.w <= yhi) && (bb.y + bb.w >= ylo);
        unsigned long long m = __ballot(pred);
        int cnt = __popcll(m);
        int pos = __popcll(m & ((1ull << lane) - 1ull));
        if (pred) {
            float4 d0 = gdat[2 * g];
            float4 d1 = gdat[2 * g + 1];
            ldsE[wv][pos][0] = make_float4(bb.x, bb.y, d0.x, d0.y);  // cx cy .5A B
            ldsE[wv][pos][1] = make_float4(d0.z, d0.w, d1.x, d1.y);  // .5C r g b
        }
        asm volatile("s_waitcnt lgkmcnt(0)" ::: "memory");
        for (int i = 0; i < cnt; ++i) {
            float4 e0 = ldsE[wv][i][0];
            float4 e1 = ldsE[wv][i][1];
            float dx = px - e0.x;
            float dy = py - e0.y;
            float sigma = fmaf(dx, fmaf(e0.z, dx, e0.w * dy), e1.x * dy * dy);
            float a = __expf(-sigma);
            a = (a >= (1.0f / 255.0f)) ? a : 0.f;
            ar = fmaf(a, e1.y, ar);
            ag = fmaf(a, e1.z, ag);
            ab = fmaf(a, e1.w, ab);
        }
    }
    red[wv][lane][0] = ar; red[wv][lane][1] = ag; red[wv][lane][2] = ab;
    __syncthreads();
    if (wv == 0) {
        float r_ = red[0][lane][0] + red[1][lane][0] + red[2][lane][0] + red[3][lane][0];
        float g_ = red[0][lane][1] + red[1][lane][1] + red[2][lane][1] + red[3][lane][1];
        float b_ = red[0][lane][2] + red[1][lane][2] + red[2][lane][2] + red[3][lane][2];
        int pix = (ty0 + (lane >> 3)) * HW + tx0 + (lane & 7);
        out[pix]            = fminf(fmaxf(r_, 0.f), 1.f);
        out[NPIX + pix]     = fminf(fmaxf(g_, 0.f), 1.f);
        out[2 * NPIX + pix] = fminf(fmaxf(b_, 0.f), 1.f);
    }
}

extern "C" void kernel_launch(void* const* d_in, const int* in_sizes, int n_in,
                              void* d_out, int out_size, void* d_ws, size_t ws_size,
                              hipStream_t stream) {
    const float* inp = (const float*)d_in[0];
    const float* cw  = (const float*)d_in[1];
    const float* cb  = (const float*)d_in[2];
    const float* w1o = (const float*)d_in[3];
    const float* b1o = (const float*)d_in[4];
    const float* ow2 = (const float*)d_in[5];
    const float* ob2 = (const float*)d_in[6];
    const float* w1s = (const float*)d_in[7];
    const float* b1s = (const float*)d_in[8];
    const float* sw2 = (const float*)d_in[9];
    const float* sb2 = (const float*)d_in[10];
    const float* w1r = (const float*)d_in[11];
    const float* b1r = (const float*)d_in[12];
    const float* rw2 = (const float*)d_in[13];
    const float* rb2 = (const float*)d_in[14];
    const float* w1c = (const float*)d_in[15];
    const float* b1c = (const float*)d_in[16];
    const float* cw2 = (const float*)d_in[17];
    const float* cb2 = (const float*)d_in[18];

    float* ws = (float*)d_ws;
    float*    hid  = ws;                               // 2359296 f
    float4*   gbox = (float4*)(ws + 2359296);          // 2304 float4
    float4*   gdat = (float4*)(ws + 2368512);          // 4608 float4
    ushort_t* Ahi  = (ushort_t*)(ws + 2386944);        // 663552 us
    ushort_t* Alo  = (ushort_t*)(ws + 2718720);        // 663552 us
    ushort_t* Bph  = (ushort_t*)(ws + 3050496);        // 294912 us
    ushort_t* Bpl  = (ushort_t*)(ws + 3197952);        // 294912 us
    float* out = (float*)d_out;

    hipLaunchKernelGGL(prep_k, dim3(720), dim3(256), 0, stream,
                       inp, cw, cb, w1o, w1s, w1r, w1c, Ahi, Alo, Bph, Bpl);
    hipLaunchKernelGGL(gemm_k, dim3(576), dim3(256), 0, stream,
                       Ahi, Alo, Bph, Bpl, b1o, b1s, b1r, b1c, hid);
    hipLaunchKernelGGL(head_k, dim3(576), dim3(256), 0, stream,
                       hid, ow2, ob2, sw2, sb2, rw2, rb2, cw2, cb2, gbox, gdat);
    hipLaunchKernelGGL(render_k, dim3(576), dim3(256), 0, stream,
                       gbox, gdat, out);
}